// Round 5
// baseline (207.845 us; speedup 1.0000x reference)
//
#include <hip/hip_runtime.h>
#include <hip/hip_bf16.h>
#include <cstdint>
#include <cstddef>

#define NROWS 16384
#define DDIM  256
#define SPLITS 16                  // 128 row-blocks x 16 col-splits = 2048 blocks

typedef __attribute__((ext_vector_type(4))) float f32x4;
typedef __attribute__((ext_vector_type(4))) float fl4;
typedef __attribute__((ext_vector_type(4))) int   i32x4;
typedef __attribute__((ext_vector_type(8))) int   i32x8;

constexpr float SCALE_EXP2 = 20.609929155556627f; // log2(e)/0.07 folded into qn
constexpr float LN2F       = 0.69314718055994531f;
constexpr float INV_T      = 14.285714285714286f;

// ---- kernel 1: one wave per row i: normalize q_i,k_i -> fp8 (q side pre-scaled
// by log2(e)/T), fp32 diag_i, zero rowsum. No LDS, no barriers.
__global__ __launch_bounds__(256) void norm_kernel(
    const float* __restrict__ q, const float* __restrict__ k,
    unsigned char* __restrict__ qn, unsigned char* __restrict__ kn,
    float* __restrict__ diag, float* __restrict__ rowsum,
    float* __restrict__ out)
{
  const int wave = threadIdx.x >> 6, lane = threadIdx.x & 63;
  const int row = blockIdx.x * 4 + wave;
  const size_t off = (size_t)row * DDIM + lane * 4;

  fl4 vq = *(const fl4*)(q + off);
  fl4 vk = *(const fl4*)(k + off);
  float ssq = vq.x * vq.x + vq.y * vq.y + vq.z * vq.z + vq.w * vq.w;
  float ssk = vk.x * vk.x + vk.y * vk.y + vk.z * vk.z + vk.w * vk.w;
  float dot = vq.x * vk.x + vq.y * vk.y + vq.z * vk.z + vq.w * vk.w;
#pragma unroll
  for (int m = 1; m < 64; m <<= 1) {
    ssq += __shfl_xor(ssq, m, 64);
    ssk += __shfl_xor(ssk, m, 64);
    dot += __shfl_xor(dot, m, 64);
  }
  float rq = 1.0f / fmaxf(sqrtf(ssq), 1e-12f);
  float rk = 1.0f / fmaxf(sqrtf(ssk), 1e-12f);

  float sq = rq * SCALE_EXP2;   // fold exp2 scale into q side
  int pq = __builtin_amdgcn_cvt_pk_fp8_f32(vq.x * sq, vq.y * sq, 0, false);
  pq     = __builtin_amdgcn_cvt_pk_fp8_f32(vq.z * sq, vq.w * sq, pq, true);
  *(int*)(qn + off) = pq;
  int pk = __builtin_amdgcn_cvt_pk_fp8_f32(vk.x * rk, vk.y * rk, 0, false);
  pk     = __builtin_amdgcn_cvt_pk_fp8_f32(vk.z * rk, vk.w * rk, pk, true);
  *(int*)(kn + off) = pk;

  if (lane == 0) {
    diag[row]   = dot * rq * rk * INV_T;
    rowsum[row] = 0.0f;
    if (row == 0) out[0] = 0.0f;
  }
}

// ---- kernel 2 (v5b): BARRIER-FREE, LDS-FREE. R3 post-mortem: MFMA-busy is a
// constant ~29us across v1-v4 while wall sat at 72-81us with no saturated pipe
// -> the 2-phase {vmcnt(0) drain + s_barrier} per 16KB tile phase-locked all
// waves onto one shared dependency (m233's 72%-overhead structure). Fix: drop
// LDS staging entirely. B-fragments load straight from global: kn is 4MB and
// split=bid%SPLITS gives each XCD only 2 splits = 512KB working set -> L2-hot.
// Each lane reads kn[n][quad*32..] (32 contiguous B) = exactly what the
// swizzled ds_read delivered. Register double-buffer, one 16-col step ahead;
// waves free-run (3/SIMD at ~160 VGPR), L2 latency (~200cy) hides under each
// step's 8 MFMA + 16 exp2 (~400cy). E/O deferred-epilogue retained.
// v5b fix (R4 container crash): v5's final-iteration prefetch read col-step 32
// = up to kn+4.198MB = ws+8.198MB, PAST the workspace regions -> page fault.
// Main loop now runs 15 iters; the 16th is peeled with no beyond-end prefetch.
// __launch_bounds__(256) ONLY -- any min-waves arg splits the unified file and
// spills the A-hoard (R4/R5: 133MB-1GB scratch traffic).
__global__ __launch_bounds__(256) void lse_kernel(
    const unsigned char* __restrict__ qn, const unsigned char* __restrict__ kn,
    float* __restrict__ rowsum)
{
  const int tid  = threadIdx.x;
  const int wave = tid >> 6, lane = tid & 63;
  const int l15  = lane & 15, quad = lane >> 4;
  const int wr   = wave >> 1, wc = wave & 1;   // 2x2 wave grid
  const int split = blockIdx.x % SPLITS;
  const int rb    = blockIdx.x / SPLITS;
  const int wrow  = rb * 128 + wr * 64;        // this wave's 64 rows
  const int col0  = split * (NROWS / SPLITS) + wc * 512;  // wave's 512 cols

  // A fragments: 4 subtiles x 2 K-steps(128) x 32B/lane = 64 VGPRs.
  // Layout (16x16x128 f8f6f4): m = lane&15, k = quad*32 + j.
  i32x8 A00, A01, A10, A11, A20, A21, A30, A31;
  {
    const unsigned char* ap0 = qn + (size_t)(wrow      + l15) * DDIM + quad * 32;
    const unsigned char* ap1 = qn + (size_t)(wrow + 16 + l15) * DDIM + quad * 32;
    const unsigned char* ap2 = qn + (size_t)(wrow + 32 + l15) * DDIM + quad * 32;
    const unsigned char* ap3 = qn + (size_t)(wrow + 48 + l15) * DDIM + quad * 32;
    A00 = *(const i32x8*)(ap0);  A01 = *(const i32x8*)(ap0 + 128);
    A10 = *(const i32x8*)(ap1);  A11 = *(const i32x8*)(ap1 + 128);
    A20 = *(const i32x8*)(ap2);  A21 = *(const i32x8*)(ap2 + 128);
    A30 = *(const i32x8*)(ap3);  A31 = *(const i32x8*)(ap3 + 128);
  }

  // B base: lane (l15,quad) serves output col n = col0 + cs*16 + l15,
  // k-bytes quad*32..+31 (kstep0) and +128 (kstep1). Advance 16 cols = 4096 B.
  const unsigned char* kb = kn + (size_t)(col0 + l15) * DDIM + quad * 32;

  f32x4 sums0 = {0.f,0.f,0.f,0.f}, sums1 = {0.f,0.f,0.f,0.f};
  f32x4 sums2 = {0.f,0.f,0.f,0.f}, sums3 = {0.f,0.f,0.f,0.f};
  f32x4 accE0, accE1, accE2, accE3, accO0, accO1, accO2, accO3;
  accO0 = (f32x4){-1e30f, -1e30f, -1e30f, -1e30f};  // exp2 -> 0 on first epilogue
  accO1 = accO0; accO2 = accO0; accO3 = accO0;

  // prologue: B for col-step 0
  i32x8 b0c = *(const i32x8*)(kb);
  i32x8 b1c = *(const i32x8*)(kb + 128);

#define EPI1(Pv, Sv) do {                                                     \
    f32x4 e_;                                                                 \
    e_[0] = __builtin_amdgcn_exp2f(Pv[0]);                                    \
    e_[1] = __builtin_amdgcn_exp2f(Pv[1]);                                    \
    e_[2] = __builtin_amdgcn_exp2f(Pv[2]);                                    \
    e_[3] = __builtin_amdgcn_exp2f(Pv[3]);                                    \
    Sv += e_;                                                                 \
  } while (0)

#define EPI(P) do {                                                           \
    EPI1(P##0, sums0); EPI1(P##1, sums1);                                     \
    EPI1(P##2, sums2); EPI1(P##3, sums3);                                     \
  } while (0)

#define MFMA8(C, B0, B1) do {                                                 \
    __builtin_amdgcn_s_setprio(1);                                            \
    C##0 = __builtin_amdgcn_mfma_scale_f32_16x16x128_f8f6f4(                  \
        A00, B0, (f32x4){0.f, 0.f, 0.f, 0.f}, 0, 0, 0, 127, 0, 127);          \
    C##1 = __builtin_amdgcn_mfma_scale_f32_16x16x128_f8f6f4(                  \
        A10, B0, (f32x4){0.f, 0.f, 0.f, 0.f}, 0, 0, 0, 127, 0, 127);          \
    C##2 = __builtin_amdgcn_mfma_scale_f32_16x16x128_f8f6f4(                  \
        A20, B0, (f32x4){0.f, 0.f, 0.f, 0.f}, 0, 0, 0, 127, 0, 127);          \
    C##3 = __builtin_amdgcn_mfma_scale_f32_16x16x128_f8f6f4(                  \
        A30, B0, (f32x4){0.f, 0.f, 0.f, 0.f}, 0, 0, 0, 127, 0, 127);          \
    C##0 = __builtin_amdgcn_mfma_scale_f32_16x16x128_f8f6f4(                  \
        A01, B1, C##0, 0, 0, 0, 127, 0, 127);                                 \
    C##1 = __builtin_amdgcn_mfma_scale_f32_16x16x128_f8f6f4(                  \
        A11, B1, C##1, 0, 0, 0, 127, 0, 127);                                 \
    C##2 = __builtin_amdgcn_mfma_scale_f32_16x16x128_f8f6f4(                  \
        A21, B1, C##2, 0, 0, 0, 127, 0, 127);                                 \
    C##3 = __builtin_amdgcn_mfma_scale_f32_16x16x128_f8f6f4(                  \
        A31, B1, C##3, 0, 0, 0, 127, 0, 127);                                 \
    __builtin_amdgcn_s_setprio(0);                                            \
  } while (0)

  // 32 col-steps of 16 cols, unrolled x2 (E/O acc ping-pong).
  // 15 full iterations; 16th peeled below (no beyond-end prefetch).
  for (int it = 0; it < 15; ++it) {
    // prefetch odd step's B (used ~400cy later, after EPI+MFMA8)
    i32x8 b0n = *(const i32x8*)(kb + 4096);
    i32x8 b1n = *(const i32x8*)(kb + 4096 + 128);
    EPI(accO);                 // exp2 of previous odd step while loads fly
    MFMA8(accE, b0c, b1c);     // even step
    // prefetch next even step's B (overwrites consumed b0c/b1c)
    b0c = *(const i32x8*)(kb + 8192);
    b1c = *(const i32x8*)(kb + 8192 + 128);
    EPI(accE);                 // exp2 of even step
    MFMA8(accO, b0n, b1n);     // odd step
    kb += 8192;
  }
  {
    // tail: col-steps 30 (b0c/b1c) and 31 (kb+4096) -- both in-bounds; no
    // further prefetch (v5's step-32 read was the OOB crash).
    i32x8 b0n = *(const i32x8*)(kb + 4096);
    i32x8 b1n = *(const i32x8*)(kb + 4096 + 128);
    EPI(accO);
    MFMA8(accE, b0c, b1c);
    EPI(accE);
    MFMA8(accO, b0n, b1n);
  }
  EPI(accO);  // drain the final pending accumulator

#undef MFMA8
#undef EPI
#undef EPI1

  // C/D: col = lane&15 (16 kn cols), row = quad*4 + r. Reduce over l15 group.
#define RED(Sv, SROW) do {                                                    \
    _Pragma("unroll")                                                         \
    for (int r = 0; r < 4; ++r) {                                             \
      float v = Sv[r];                                                        \
      v += __shfl_xor(v, 1, 64);                                              \
      v += __shfl_xor(v, 2, 64);                                              \
      v += __shfl_xor(v, 4, 64);                                              \
      v += __shfl_xor(v, 8, 64);                                              \
      if (l15 == 0) atomicAdd(&rowsum[(SROW) + quad * 4 + r], v);             \
    }                                                                         \
  } while (0)

  RED(sums0, wrow);
  RED(sums1, wrow + 16);
  RED(sums2, wrow + 32);
  RED(sums3, wrow + 48);
#undef RED
}

// ---- kernel 3: out = mean(ln(rowsum) - diag)
__global__ void final_kernel(const float* __restrict__ rowsum,
                             const float* __restrict__ diag,
                             float* __restrict__ out)
{
  int row = blockIdx.x * 256 + threadIdx.x;
  float c = __builtin_amdgcn_logf(rowsum[row]) * LN2F - diag[row];
#pragma unroll
  for (int m = 1; m < 64; m <<= 1) c += __shfl_xor(c, m, 64);
  __shared__ float red[4];
  int wave = threadIdx.x >> 6, lane = threadIdx.x & 63;
  if (lane == 0) red[wave] = c;
  __syncthreads();
  if (threadIdx.x == 0) {
    float s = red[0] + red[1] + red[2] + red[3];
    atomicAdd(out, s * (1.0f / NROWS));
  }
}

extern "C" void kernel_launch(void* const* d_in, const int* in_sizes, int n_in,
                              void* d_out, int out_size, void* d_ws, size_t ws_size,
                              hipStream_t stream)
{
  const float* q = (const float*)d_in[0];
  const float* k = (const float*)d_in[1];
  float* out = (float*)d_out;

  char* ws = (char*)d_ws;
  unsigned char* qn = (unsigned char*)ws;                    // 4 MB
  unsigned char* kn = (unsigned char*)(ws + (4u << 20));     // 4 MB
  float* diag   = (float*)(ws + (8u << 20));                 // 64 KB
  float* rowsum = (float*)(ws + (8u << 20) + (64u << 10));   // 64 KB

  norm_kernel <<<NROWS / 4, 256, 0, stream>>>(q, k, qn, kn, diag, rowsum, out);
  lse_kernel  <<<(NROWS / 128) * SPLITS, 256, 0, stream>>>(qn, kn, rowsum);
  final_kernel<<<NROWS / 256, 256, 0, stream>>>(rowsum, diag, out);
}

// Round 6
// 153.174 us; speedup vs baseline: 1.3569x; 1.3569x over previous
//
#include <hip/hip_runtime.h>
#include <hip/hip_bf16.h>
#include <cstdint>
#include <cstddef>

#define NROWS 16384
#define DDIM  256
#define SPLITS 16                  // 128 row-blocks x 16 col-splits = 2048 blocks
#define NTILES 256                 // 16384 cols / 64
#define TILES_PER (NTILES / SPLITS)

typedef __attribute__((ext_vector_type(4))) float f32x4;
typedef __attribute__((ext_vector_type(4))) float fl4;
typedef __attribute__((ext_vector_type(4))) int   i32x4;
typedef __attribute__((ext_vector_type(8))) int   i32x8;

constexpr float SCALE_EXP2 = 20.609929155556627f; // log2(e)/0.07 folded into qn
constexpr float LN2F       = 0.69314718055994531f;
constexpr float INV_T      = 14.285714285714286f;

__device__ inline void gload_lds16(const void* g, void* l) {
  __builtin_amdgcn_global_load_lds(
      (const __attribute__((address_space(1))) void*)g,
      (__attribute__((address_space(3))) void*)l, 16, 0, 0);
}

// ---- kernel 1: one wave per row i: normalize q_i,k_i -> fp8 (q side pre-scaled
// by log2(e)/T), fp32 diag_i, zero rowsum. No LDS, no barriers.
__global__ __launch_bounds__(256) void norm_kernel(
    const float* __restrict__ q, const float* __restrict__ k,
    unsigned char* __restrict__ qn, unsigned char* __restrict__ kn,
    float* __restrict__ diag, float* __restrict__ rowsum,
    float* __restrict__ out)
{
  const int wave = threadIdx.x >> 6, lane = threadIdx.x & 63;
  const int row = blockIdx.x * 4 + wave;
  const size_t off = (size_t)row * DDIM + lane * 4;

  fl4 vq = *(const fl4*)(q + off);
  fl4 vk = *(const fl4*)(k + off);
  float ssq = vq.x * vq.x + vq.y * vq.y + vq.z * vq.z + vq.w * vq.w;
  float ssk = vk.x * vk.x + vk.y * vk.y + vk.z * vk.z + vk.w * vk.w;
  float dot = vq.x * vk.x + vq.y * vk.y + vq.z * vk.z + vq.w * vk.w;
#pragma unroll
  for (int m = 1; m < 64; m <<= 1) {
    ssq += __shfl_xor(ssq, m, 64);
    ssk += __shfl_xor(ssk, m, 64);
    dot += __shfl_xor(dot, m, 64);
  }
  float rq = 1.0f / fmaxf(sqrtf(ssq), 1e-12f);
  float rk = 1.0f / fmaxf(sqrtf(ssk), 1e-12f);

  float sq = rq * SCALE_EXP2;   // fold exp2 scale into q side
  int pq = __builtin_amdgcn_cvt_pk_fp8_f32(vq.x * sq, vq.y * sq, 0, false);
  pq     = __builtin_amdgcn_cvt_pk_fp8_f32(vq.z * sq, vq.w * sq, pq, true);
  *(int*)(qn + off) = pq;
  int pk = __builtin_amdgcn_cvt_pk_fp8_f32(vk.x * rk, vk.y * rk, 0, false);
  pk     = __builtin_amdgcn_cvt_pk_fp8_f32(vk.z * rk, vk.w * rk, pk, true);
  *(int*)(kn + off) = pk;

  if (lane == 0) {
    diag[row]   = dot * rq * rk * INV_T;
    rowsum[row] = 0.0f;
    if (row == 0) out[0] = 0.0f;
  }
}

// ---- kernel 2 (v6): v2 structure + TWO fixes from the R5 post-mortem.
// (a) SPLIT ACCUMULATORS: v1-v5 chained kstep0->kstep1 through the MFMA C
//     operand (acc = mfma(A1,b1, mfma(A0,b0,0))): a depth-2 dependent chain.
//     With issue ~35cy/SIMD and dep-latency ~4x, that caps the matrix pipe
//     near 40% -- EXACTLY the 34-41% MfmaUtil measured on every variant,
//     insensitive to staging/occupancy/tiling. Now kstep0 -> accA, kstep1 ->
//     accB, both C-in=0, fully independent; EPI computes exp2(accA+accB).
// (b) A-PIN: VGPR_Count 48-80 across v2-v5b proves the compiler rematerializes
//     the A-fragment global loads inside the loop (the hoard alone is 32+
//     VGPRs). asm volatile "+v" pins force one materialization, resident.
// Staging: v2's double-buffered LDS, vmcnt(0)+barrier per 16KB tile (v3
// triple-buffer and v5 global-direct both measured SLOWER -- reverted).
// CRITICAL (R6 NaN post-mortem): __syncthreads() does NOT drain LDS-DMA vmcnt
// -- the explicit s_waitcnt before it is required.
// __launch_bounds__(256) ONLY -- any min-waves arg splits the unified file and
// spills the A-hoard (R4/R5: 133MB-1GB scratch traffic).
__global__ __launch_bounds__(256) void lse_kernel(
    const unsigned char* __restrict__ qn, const unsigned char* __restrict__ kn,
    float* __restrict__ rowsum)
{
  __shared__ __attribute__((aligned(16))) unsigned char Bs[2][64 * DDIM]; // 2 x 16 KB

  const int tid  = threadIdx.x;
  const int wave = tid >> 6, lane = tid & 63;
  const int l15  = lane & 15, quad = lane >> 4;
  const int split = blockIdx.x % SPLITS;
  const int rb    = blockIdx.x / SPLITS;
  const int wrow  = rb * 128 + wave * 32;      // v2 geometry: 4 waves x 32 rows
  const int t0 = split * TILES_PER;
  const int t1 = t0 + TILES_PER;

  // Staging addresses (i-invariant): chunk L = i*256+tid -> row n = i*16+Ln,
  // slot jj = tid&15 holds global chunk j = jj ^ (n&15) = Ljj ^ Ln.
  const int Ln = tid >> 4, Ljj = tid & 15;
  const int Lj = Ljj ^ Ln;
  const size_t src_off = (size_t)Ln * DDIM + (size_t)Lj * 16;

  // A fragments: 2 subtiles x 2 K-steps(128) x 32B/lane = 32 VGPRs.
  // Layout (16x16x128 f8f6f4): m = lane&15, k = quad*32 + j.
  i32x8 A00, A01, A10, A11;
  {
    const unsigned char* ap0 = qn + (size_t)(wrow + l15) * DDIM + quad * 32;
    const unsigned char* ap1 = qn + (size_t)(wrow + 16 + l15) * DDIM + quad * 32;
    A00 = *(const i32x8*)(ap0);
    A01 = *(const i32x8*)(ap0 + 128);
    A10 = *(const i32x8*)(ap1);
    A11 = *(const i32x8*)(ap1 + 128);
  }
  // Pin: forbid rematerialization of the loads above inside the loop.
  asm volatile("" : "+v"(A00), "+v"(A01), "+v"(A10), "+v"(A11));

  // Per-lane swizzled LDS read offsets. n = cs*16+l15 so n&15 == l15 for all
  // cs: the XOR slot pattern is cs-invariant, only +cs*4096 changes.
  const int rowoff = l15 * DDIM;
  const int c0  = quad * 2;
  const int o00 = rowoff + (((c0    ) ^ l15) * 16);
  const int o01 = rowoff + (((c0 + 1) ^ l15) * 16);
  const int o10 = rowoff + (((c0 + 8) ^ l15) * 16);
  const int o11 = rowoff + (((c0 + 9) ^ l15) * 16);

  f32x4 sums0 = {0.f, 0.f, 0.f, 0.f}, sums1 = {0.f, 0.f, 0.f, 0.f};
  // Split accumulators: xA = kstep0 partial, xB = kstep1 partial; E/O ping-pong.
  f32x4 aEA0, aEB0, aEA1, aEB1, aOA0, aOB0, aOA1, aOB1;
  aOA0 = (f32x4){-1e30f, -1e30f, -1e30f, -1e30f};  // exp2(A+B) -> 0 on first EPI
  aOB0 = aOA0; aOA1 = aOA0; aOB1 = aOA0;

  // prefetch first tile into buffer 0
  {
    const unsigned char* kbase = kn + (size_t)t0 * (64 * DDIM) + src_off;
#pragma unroll
    for (int i = 0; i < 4; ++i)
      gload_lds16(kbase + i * 4096, (void*)(Bs[0] + tid * 16 + i * 4096));
  }

#define EPI(P) do {                                                           \
    f32x4 t0_ = P##A0 + P##B0;                                                \
    f32x4 t1_ = P##A1 + P##B1;                                                \
    f32x4 e0_, e1_;                                                           \
    e0_[0] = __builtin_amdgcn_exp2f(t0_[0]);                                  \
    e0_[1] = __builtin_amdgcn_exp2f(t0_[1]);                                  \
    e0_[2] = __builtin_amdgcn_exp2f(t0_[2]);                                  \
    e0_[3] = __builtin_amdgcn_exp2f(t0_[3]);                                  \
    e1_[0] = __builtin_amdgcn_exp2f(t1_[0]);                                  \
    e1_[1] = __builtin_amdgcn_exp2f(t1_[1]);                                  \
    e1_[2] = __builtin_amdgcn_exp2f(t1_[2]);                                  \
    e1_[3] = __builtin_amdgcn_exp2f(t1_[3]);                                  \
    sums0 += e0_;                                                             \
    sums1 += e1_;                                                             \
  } while (0)

#define CS_STEP(C, P, BOFF) do {                                              \
    i32x4 lo0_ = *(const i32x4*)(bb + (BOFF) + o00);                          \
    i32x4 hi0_ = *(const i32x4*)(bb + (BOFF) + o01);                          \
    i32x4 lo1_ = *(const i32x4*)(bb + (BOFF) + o10);                          \
    i32x4 hi1_ = *(const i32x4*)(bb + (BOFF) + o11);                          \
    EPI(P); /* exp2 of previous cs while ds_reads fly */                      \
    i32x8 b0_ = {lo0_.x, lo0_.y, lo0_.z, lo0_.w, hi0_.x, hi0_.y, hi0_.z, hi0_.w}; \
    i32x8 b1_ = {lo1_.x, lo1_.y, lo1_.z, lo1_.w, hi1_.x, hi1_.y, hi1_.z, hi1_.w}; \
    __builtin_amdgcn_s_setprio(1);                                            \
    /* 4 INDEPENDENT MFMAs: no C-operand chain (R5 fix a) */                  \
    C##A0 = __builtin_amdgcn_mfma_scale_f32_16x16x128_f8f6f4(                 \
        A00, b0_, (f32x4){0.f, 0.f, 0.f, 0.f}, 0, 0, 0, 127, 0, 127);         \
    C##A1 = __builtin_amdgcn_mfma_scale_f32_16x16x128_f8f6f4(                 \
        A10, b0_, (f32x4){0.f, 0.f, 0.f, 0.f}, 0, 0, 0, 127, 0, 127);         \
    C##B0 = __builtin_amdgcn_mfma_scale_f32_16x16x128_f8f6f4(                 \
        A01, b1_, (f32x4){0.f, 0.f, 0.f, 0.f}, 0, 0, 0, 127, 0, 127);         \
    C##B1 = __builtin_amdgcn_mfma_scale_f32_16x16x128_f8f6f4(                 \
        A11, b1_, (f32x4){0.f, 0.f, 0.f, 0.f}, 0, 0, 0, 127, 0, 127);         \
    __builtin_amdgcn_s_setprio(0);                                            \
  } while (0)

  for (int ct = t0; ct < t1; ++ct) {
    const int cur = (ct - t0) & 1;
    __builtin_amdgcn_s_waitcnt(0x0F70);  // vmcnt(0): drain buf[cur]'s LDS-DMA
    __syncthreads();                     // + all waves done reading buf[cur^1]
    if (ct + 1 < t1) {
      const unsigned char* kbase = kn + (size_t)(ct + 1) * (64 * DDIM) + src_off;
#pragma unroll
      for (int i = 0; i < 4; ++i)
        gload_lds16(kbase + i * 4096, (void*)(Bs[cur ^ 1] + tid * 16 + i * 4096));
    }
    const unsigned char* bb = Bs[cur];
    // parity ping-pong: even cs -> aE (epilogue aO), odd cs -> aO (epilogue aE)
    CS_STEP(aE, aO, 0);
    CS_STEP(aO, aE, 4096);
    CS_STEP(aE, aO, 8192);
    CS_STEP(aO, aE, 12288);
  }
  EPI(aO);  // drain the final pending accumulator

#undef CS_STEP
#undef EPI

  // C/D: col = lane&15 (the 16 kn columns), row = quad*4 + r. Reduce over l15.
#pragma unroll
  for (int r = 0; r < 4; ++r) {
    float v0 = sums0[r], v1 = sums1[r];
    v0 += __shfl_xor(v0, 1, 64);  v1 += __shfl_xor(v1, 1, 64);
    v0 += __shfl_xor(v0, 2, 64);  v1 += __shfl_xor(v1, 2, 64);
    v0 += __shfl_xor(v0, 4, 64);  v1 += __shfl_xor(v1, 4, 64);
    v0 += __shfl_xor(v0, 8, 64);  v1 += __shfl_xor(v1, 8, 64);
    if (l15 == 0) {
      atomicAdd(&rowsum[wrow + quad * 4 + r], v0);
      atomicAdd(&rowsum[wrow + 16 + quad * 4 + r], v1);
    }
  }
}

// ---- kernel 3: out = mean(ln(rowsum) - diag)
__global__ void final_kernel(const float* __restrict__ rowsum,
                             const float* __restrict__ diag,
                             float* __restrict__ out)
{
  int row = blockIdx.x * 256 + threadIdx.x;
  float c = __builtin_amdgcn_logf(rowsum[row]) * LN2F - diag[row];
#pragma unroll
  for (int m = 1; m < 64; m <<= 1) c += __shfl_xor(c, m, 64);
  __shared__ float red[4];
  int wave = threadIdx.x >> 6, lane = threadIdx.x & 63;
  if (lane == 0) red[wave] = c;
  __syncthreads();
  if (threadIdx.x == 0) {
    float s = red[0] + red[1] + red[2] + red[3];
    atomicAdd(out, s * (1.0f / NROWS));
  }
}

extern "C" void kernel_launch(void* const* d_in, const int* in_sizes, int n_in,
                              void* d_out, int out_size, void* d_ws, size_t ws_size,
                              hipStream_t stream)
{
  const float* q = (const float*)d_in[0];
  const float* k = (const float*)d_in[1];
  float* out = (float*)d_out;

  char* ws = (char*)d_ws;
  unsigned char* qn = (unsigned char*)ws;                    // 4 MB
  unsigned char* kn = (unsigned char*)(ws + (4u << 20));     // 4 MB
  float* diag   = (float*)(ws + (8u << 20));                 // 64 KB
  float* rowsum = (float*)(ws + (8u << 20) + (64u << 10));   // 64 KB

  norm_kernel <<<NROWS / 4, 256, 0, stream>>>(q, k, qn, kn, diag, rowsum, out);
  lse_kernel  <<<(NROWS / 128) * SPLITS, 256, 0, stream>>>(qn, kn, rowsum);
  final_kernel<<<NROWS / 256, 256, 0, stream>>>(rowsum, diag, out);
}

// Round 7
// 143.624 us; speedup vs baseline: 1.4471x; 1.0665x over previous
//
#include <hip/hip_runtime.h>
#include <hip/hip_bf16.h>
#include <cstdint>
#include <cstddef>

#define NROWS 16384
#define DDIM  256
#define SPLITS 16                  // 128 row-blocks x 16 col-splits = 2048 blocks
#define NTILES 256                 // 16384 cols / 64
#define TILES_PER (NTILES / SPLITS)

typedef __attribute__((ext_vector_type(4))) float f32x4;
typedef __attribute__((ext_vector_type(4))) float fl4;
typedef __attribute__((ext_vector_type(4))) int   i32x4;
typedef __attribute__((ext_vector_type(8))) int   i32x8;

constexpr float SCALE_EXP2 = 20.609929155556627f; // log2(e)/0.07 folded into qn
constexpr float LN2F       = 0.69314718055994531f;
constexpr float INV_T      = 14.285714285714286f;

__device__ inline void gload_lds16(const void* g, void* l) {
  __builtin_amdgcn_global_load_lds(
      (const __attribute__((address_space(1))) void*)g,
      (__attribute__((address_space(3))) void*)l, 16, 0, 0);
}

// ---- kernel 1: one wave per row i: normalize q_i,k_i -> fp8 (q side pre-scaled
// by log2(e)/T), fp32 diag_i, zero rowsum. No LDS, no barriers.
__global__ __launch_bounds__(256) void norm_kernel(
    const float* __restrict__ q, const float* __restrict__ k,
    unsigned char* __restrict__ qn, unsigned char* __restrict__ kn,
    float* __restrict__ diag, float* __restrict__ rowsum,
    float* __restrict__ out)
{
  const int wave = threadIdx.x >> 6, lane = threadIdx.x & 63;
  const int row = blockIdx.x * 4 + wave;
  const size_t off = (size_t)row * DDIM + lane * 4;

  fl4 vq = *(const fl4*)(q + off);
  fl4 vk = *(const fl4*)(k + off);
  float ssq = vq.x * vq.x + vq.y * vq.y + vq.z * vq.z + vq.w * vq.w;
  float ssk = vk.x * vk.x + vk.y * vk.y + vk.z * vk.z + vk.w * vk.w;
  float dot = vq.x * vk.x + vq.y * vk.y + vq.z * vk.z + vq.w * vk.w;
#pragma unroll
  for (int m = 1; m < 64; m <<= 1) {
    ssq += __shfl_xor(ssq, m, 64);
    ssk += __shfl_xor(ssk, m, 64);
    dot += __shfl_xor(dot, m, 64);
  }
  float rq = 1.0f / fmaxf(sqrtf(ssq), 1e-12f);
  float rk = 1.0f / fmaxf(sqrtf(ssk), 1e-12f);

  float sq = rq * SCALE_EXP2;   // fold exp2 scale into q side
  int pq = __builtin_amdgcn_cvt_pk_fp8_f32(vq.x * sq, vq.y * sq, 0, false);
  pq     = __builtin_amdgcn_cvt_pk_fp8_f32(vq.z * sq, vq.w * sq, pq, true);
  *(int*)(qn + off) = pq;
  int pk = __builtin_amdgcn_cvt_pk_fp8_f32(vk.x * rk, vk.y * rk, 0, false);
  pk     = __builtin_amdgcn_cvt_pk_fp8_f32(vk.z * rk, vk.w * rk, pk, true);
  *(int*)(kn + off) = pk;

  if (lane == 0) {
    diag[row]   = dot * rq * rk * INV_T;
    rowsum[row] = 0.0f;
    if (row == 0) out[0] = 0.0f;
  }
}

// ---- kernel 2 (v7): v2 structure + sched_group_barrier MFMA:VALU interleave.
// Session evidence: MfmaUtil(41%)x72us = 29.5us matrix + VALUBusy(49%)x72 =
// 35us VALU ~= 90% of wall -> pipes SERIALIZED. R6's split-acc probe showed
// the 1:1 tradeoff (VALU +8 adds/step: VALUBusy 48->56, MfmaUtil 41->33):
// pipe competition, not dependency latency (4 independent MFMAs gained 0%).
// m114: MFMA & VALU pipes overlap fully across waves -- IF waves offer mixed
// instruction classes. v1-v6 clustered {4xMFMA}(setprio1) then {16xVALU}:
// barrier-phase-locked waves all MFMA together / all EPI together -> idle
// pipes. Fix: (a) drop setprio (it enforced the in-phase arbitration);
// (b) T19 sched_group_barrier pins per-CS_STEP emission to
// {ds_read x4}{VALU x8}{MFMA,VALU x2}x4 -- every wave's stream alternates
// 1 MFMA : 2-8 VALU, so the SIMD scheduler keeps both pipes fed regardless
// of wave phase. Extra insts (addr/staging/waitcnt) float freely.
// Staging: v2's double-buffered LDS, vmcnt(0)+barrier per 16KB tile (v3
// triple-buffer, v4 2x2-tile, v5 global-direct all measured slower).
// CRITICAL (R6 NaN post-mortem): __syncthreads() does NOT drain LDS-DMA vmcnt
// -- the explicit s_waitcnt before it is required.
// __launch_bounds__(256) ONLY -- any min-waves arg splits the unified file and
// spills the A-hoard (R4/R5: 133MB-1GB scratch traffic).
__global__ __launch_bounds__(256) void lse_kernel(
    const unsigned char* __restrict__ qn, const unsigned char* __restrict__ kn,
    float* __restrict__ rowsum)
{
  __shared__ __attribute__((aligned(16))) unsigned char Bs[2][64 * DDIM]; // 2 x 16 KB

  const int tid  = threadIdx.x;
  const int wave = tid >> 6, lane = tid & 63;
  const int l15  = lane & 15, quad = lane >> 4;
  const int split = blockIdx.x % SPLITS;
  const int rb    = blockIdx.x / SPLITS;
  const int wrow  = rb * 128 + wave * 32;      // v2 geometry: 4 waves x 32 rows
  const int t0 = split * TILES_PER;
  const int t1 = t0 + TILES_PER;

  // Staging addresses (i-invariant): chunk L = i*256+tid -> row n = i*16+Ln,
  // slot jj = tid&15 holds global chunk j = jj ^ (n&15) = Ljj ^ Ln.
  const int Ln = tid >> 4, Ljj = tid & 15;
  const int Lj = Ljj ^ Ln;
  const size_t src_off = (size_t)Ln * DDIM + (size_t)Lj * 16;

  // A fragments: 2 subtiles x 2 K-steps(128) x 32B/lane = 32 VGPRs.
  // Layout (16x16x128 f8f6f4): m = lane&15, k = quad*32 + j.
  i32x8 A00, A01, A10, A11;
  {
    const unsigned char* ap0 = qn + (size_t)(wrow + l15) * DDIM + quad * 32;
    const unsigned char* ap1 = qn + (size_t)(wrow + 16 + l15) * DDIM + quad * 32;
    A00 = *(const i32x8*)(ap0);
    A01 = *(const i32x8*)(ap0 + 128);
    A10 = *(const i32x8*)(ap1);
    A11 = *(const i32x8*)(ap1 + 128);
  }
  // Pin: discourage rematerialization of the loads above inside the loop.
  asm volatile("" : "+v"(A00), "+v"(A01), "+v"(A10), "+v"(A11));

  // Per-lane swizzled LDS read offsets. n = cs*16+l15 so n&15 == l15 for all
  // cs: the XOR slot pattern is cs-invariant, only +cs*4096 changes.
  const int rowoff = l15 * DDIM;
  const int c0  = quad * 2;
  const int o00 = rowoff + (((c0    ) ^ l15) * 16);
  const int o01 = rowoff + (((c0 + 1) ^ l15) * 16);
  const int o10 = rowoff + (((c0 + 8) ^ l15) * 16);
  const int o11 = rowoff + (((c0 + 9) ^ l15) * 16);

  f32x4 sums0 = {0.f, 0.f, 0.f, 0.f}, sums1 = {0.f, 0.f, 0.f, 0.f};
  f32x4 accE0, accE1, accO0, accO1;
  accO0 = (f32x4){-1e30f, -1e30f, -1e30f, -1e30f};  // exp2 -> 0 on first epilogue
  accO1 = accO0;

  // prefetch first tile into buffer 0
  {
    const unsigned char* kbase = kn + (size_t)t0 * (64 * DDIM) + src_off;
#pragma unroll
    for (int i = 0; i < 4; ++i)
      gload_lds16(kbase + i * 4096, (void*)(Bs[0] + tid * 16 + i * 4096));
  }

#define SGB(mask, n) __builtin_amdgcn_sched_group_barrier((mask), (n), 0)

#define EPI(P0, P1) do {                                                      \
    f32x4 e0_, e1_;                                                           \
    e0_[0] = __builtin_amdgcn_exp2f(P0[0]);                                   \
    e0_[1] = __builtin_amdgcn_exp2f(P0[1]);                                   \
    e0_[2] = __builtin_amdgcn_exp2f(P0[2]);                                   \
    e0_[3] = __builtin_amdgcn_exp2f(P0[3]);                                   \
    e1_[0] = __builtin_amdgcn_exp2f(P1[0]);                                   \
    e1_[1] = __builtin_amdgcn_exp2f(P1[1]);                                   \
    e1_[2] = __builtin_amdgcn_exp2f(P1[2]);                                   \
    e1_[3] = __builtin_amdgcn_exp2f(P1[3]);                                   \
    sums0 += e0_;                                                             \
    sums1 += e1_;                                                             \
  } while (0)

#define CS_STEP(C, P, BOFF) do {                                              \
    i32x4 lo0_ = *(const i32x4*)(bb + (BOFF) + o00);                          \
    i32x4 hi0_ = *(const i32x4*)(bb + (BOFF) + o01);                          \
    i32x4 lo1_ = *(const i32x4*)(bb + (BOFF) + o10);                          \
    i32x4 hi1_ = *(const i32x4*)(bb + (BOFF) + o11);                          \
    EPI(P##0, P##1); /* exp2 of previous cs while ds_reads fly */             \
    i32x8 b0_ = {lo0_.x, lo0_.y, lo0_.z, lo0_.w, hi0_.x, hi0_.y, hi0_.z, hi0_.w}; \
    i32x8 b1_ = {lo1_.x, lo1_.y, lo1_.z, lo1_.w, hi1_.x, hi1_.y, hi1_.z, hi1_.w}; \
    C##0 = __builtin_amdgcn_mfma_scale_f32_16x16x128_f8f6f4(                  \
        A00, b0_, (f32x4){0.f, 0.f, 0.f, 0.f}, 0, 0, 0, 127, 0, 127);         \
    C##1 = __builtin_amdgcn_mfma_scale_f32_16x16x128_f8f6f4(                  \
        A10, b0_, (f32x4){0.f, 0.f, 0.f, 0.f}, 0, 0, 0, 127, 0, 127);         \
    C##0 = __builtin_amdgcn_mfma_scale_f32_16x16x128_f8f6f4(                  \
        A01, b1_, C##0, 0, 0, 0, 127, 0, 127);                                \
    C##1 = __builtin_amdgcn_mfma_scale_f32_16x16x128_f8f6f4(                  \
        A11, b1_, C##1, 0, 0, 0, 127, 0, 127);                                \
    /* T19 pin: ds_reads up front, then 1 MFMA : small VALU packets so   */   \
    /* every wave's stream feeds BOTH pipes continuously (m114 overlap). */   \
    SGB(0x100, 4);  /* ds_read x4 (this step's B)        */                   \
    SGB(0x002, 8);  /* EPI half: 8 VALU under ds flight  */                   \
    SGB(0x008, 1);  /* MFMA                              */                   \
    SGB(0x002, 2);                                                            \
    SGB(0x008, 1);                                                            \
    SGB(0x002, 2);                                                            \
    SGB(0x008, 1);                                                            \
    SGB(0x002, 2);                                                            \
    SGB(0x008, 1);                                                            \
    SGB(0x002, 2);                                                            \
  } while (0)

  for (int ct = t0; ct < t1; ++ct) {
    const int cur = (ct - t0) & 1;
    __builtin_amdgcn_s_waitcnt(0x0F70);  // vmcnt(0): drain buf[cur]'s LDS-DMA
    __syncthreads();                     // + all waves done reading buf[cur^1]
    if (ct + 1 < t1) {
      const unsigned char* kbase = kn + (size_t)(ct + 1) * (64 * DDIM) + src_off;
#pragma unroll
      for (int i = 0; i < 4; ++i)
        gload_lds16(kbase + i * 4096, (void*)(Bs[cur ^ 1] + tid * 16 + i * 4096));
    }
    const unsigned char* bb = Bs[cur];
    // parity ping-pong: even cs -> accE (epilogue accO), odd cs -> accO
    CS_STEP(accE, accO, 0);
    CS_STEP(accO, accE, 4096);
    CS_STEP(accE, accO, 8192);
    CS_STEP(accO, accE, 12288);
  }
  EPI(accO0, accO1);  // drain the final pending accumulator

#undef CS_STEP
#undef EPI
#undef SGB

  // C/D: col = lane&15 (the 16 kn columns), row = quad*4 + r. Reduce over l15.
#pragma unroll
  for (int r = 0; r < 4; ++r) {
    float v0 = sums0[r], v1 = sums1[r];
    v0 += __shfl_xor(v0, 1, 64);  v1 += __shfl_xor(v1, 1, 64);
    v0 += __shfl_xor(v0, 2, 64);  v1 += __shfl_xor(v1, 2, 64);
    v0 += __shfl_xor(v0, 4, 64);  v1 += __shfl_xor(v1, 4, 64);
    v0 += __shfl_xor(v0, 8, 64);  v1 += __shfl_xor(v1, 8, 64);
    if (l15 == 0) {
      atomicAdd(&rowsum[wrow + quad * 4 + r], v0);
      atomicAdd(&rowsum[wrow + 16 + quad * 4 + r], v1);
    }
  }
}

// ---- kernel 3: out = mean(ln(rowsum) - diag)
__global__ void final_kernel(const float* __restrict__ rowsum,
                             const float* __restrict__ diag,
                             float* __restrict__ out)
{
  int row = blockIdx.x * 256 + threadIdx.x;
  float c = __builtin_amdgcn_logf(rowsum[row]) * LN2F - diag[row];
#pragma unroll
  for (int m = 1; m < 64; m <<= 1) c += __shfl_xor(c, m, 64);
  __shared__ float red[4];
  int wave = threadIdx.x >> 6, lane = threadIdx.x & 63;
  if (lane == 0) red[wave] = c;
  __syncthreads();
  if (threadIdx.x == 0) {
    float s = red[0] + red[1] + red[2] + red[3];
    atomicAdd(out, s * (1.0f / NROWS));
  }
}

extern "C" void kernel_launch(void* const* d_in, const int* in_sizes, int n_in,
                              void* d_out, int out_size, void* d_ws, size_t ws_size,
                              hipStream_t stream)
{
  const float* q = (const float*)d_in[0];
  const float* k = (const float*)d_in[1];
  float* out = (float*)d_out;

  char* ws = (char*)d_ws;
  unsigned char* qn = (unsigned char*)ws;                    // 4 MB
  unsigned char* kn = (unsigned char*)(ws + (4u << 20));     // 4 MB
  float* diag   = (float*)(ws + (8u << 20));                 // 64 KB
  float* rowsum = (float*)(ws + (8u << 20) + (64u << 10));   // 64 KB

  norm_kernel <<<NROWS / 4, 256, 0, stream>>>(q, k, qn, kn, diag, rowsum, out);
  lse_kernel  <<<(NROWS / 128) * SPLITS, 256, 0, stream>>>(qn, kn, rowsum);
  final_kernel<<<NROWS / 256, 256, 0, stream>>>(rowsum, diag, out);
}